// Round 3
// baseline (3505.534 us; speedup 1.0000x reference)
//
#include <hip/hip_runtime.h>
#include <stdint.h>

// ===================== Round 3 =====================
// Same proven data path as round 2 (plain HIP, [m][k] fp16 staging, b128
// A-frag reads, W B-frags prepacked). Structural change: 4 waves/block,
// 512 blocks -> 2 blocks/CU = two independent barrier groups per CU to
// hide the per-chunk barrier+vmcnt drain. W chunk = 32 hidden cols
// (16 KB, double-buffered). xb state demoted to packed fp16 to stay
// under 256 unified regs at 2 waves/SIMD.
// Predict: 1450-1650us, MfmaUtil ~40%, no scratch.
// ===================================================

typedef _Float16 half8 __attribute__((ext_vector_type(8)));
typedef float f32x4 __attribute__((ext_vector_type(4)));
typedef __attribute__((address_space(3))) char lchar;
typedef __attribute__((address_space(1))) char gchar;

#define KSTR 136  // shorts per staging row: 128 + 8 pad -> 272B rows, 2-way banks

static __device__ __forceinline__ void gload_lds16(const void* g, void* l) {
  __builtin_amdgcn_global_load_lds((const gchar*)g, (lchar*)l, 16, 0, 0);
}

static __device__ __forceinline__ unsigned short f2h(float x) {
  union { _Float16 h; unsigned short u; } cv;
  cv.h = (_Float16)x;
  return cv.u;
}
static __device__ __forceinline__ float h2f(unsigned short u) {
  union { unsigned short u; _Float16 h; } cv;
  cv.u = u;
  return (float)cv.h;
}

// Prepack W1 (128x512) + W2 (512x128) fp32 -> one fp16 B-frag stream.
// 16 chunks of 32 hidden cols; chunk c occupies 16 KB at wp + c*16384:
//   [0,8K):  W1 frags, f = nt*4 + ks   (nt: 2 of 16 cols, ks: 4 of K=128)
//   [8K,16K): W2 frags, f = 8 + nt     (nt: 8 of 16 out-cols, K-local = 32)
// B-frag (16x16x32): lane l holds B[k][n], n = l&15, k = (l>>4)*8 + j.
__global__ void pack_w(const float* __restrict__ W1, const float* __restrict__ W2,
                       unsigned short* __restrict__ wp) {
  int id = blockIdx.x * 256 + threadIdx.x;  // 0..16383
  int lane = id & 63, fid = (id >> 6) & 255;
  int g = lane >> 4, lm = lane & 15;
  int c = fid >> 4, f = fid & 15;
  if (f < 8) {
    int nt = f >> 2, ks = f & 3;
    int n = c * 32 + nt * 16 + lm;
#pragma unroll
    for (int j = 0; j < 8; ++j) {
      int k = ks * 32 + g * 8 + j;
      wp[fid * 512 + lane * 8 + j] = f2h(W1[k * 512 + n]);
    }
  } else {
    int nt = f - 8;
    int u = nt * 16 + lm;
#pragma unroll
    for (int j = 0; j < 8; ++j) {
      int k = c * 32 + g * 8 + j;
      wp[fid * 512 + lane * 8 + j] = f2h(W2[k * 128 + u]);
    }
  }
}

__global__ __launch_bounds__(256, 2) void node_rk4(
    const float* __restrict__ x0, const float* __restrict__ b1,
    const float* __restrict__ b2, const unsigned short* __restrict__ wp,
    float* __restrict__ out) {
  // LDS: 32K W dbuf + 34K staging + 2.5K biases = 70144 B -> 2 blocks/CU.
  __shared__ char Wbuf[2][16384];
  __shared__ unsigned short stg[4][32][KSTR];
  __shared__ float b1s[512];
  __shared__ float b2s[128];

  const int tid = threadIdx.x;
  const int w = tid >> 6, lane = tid & 63;
  const int g = lane >> 4, lm = lane & 15;
  unsigned short(*stage)[KSTR] = stg[w];

  b1s[tid] = b1[tid];
  b1s[tid + 256] = b1[tid + 256];
  if (tid < 128) b2s[tid] = b2[tid];

  // State: xa fp32 accumulator (C/D layout), xb base as packed fp16.
  const int rbase = blockIdx.x * 128 + w * 32;
  f32x4 xa[2][8];
  ushort4 xbh[2][8];
#pragma unroll
  for (int mt = 0; mt < 2; ++mt)
#pragma unroll
    for (int t = 0; t < 8; ++t) {
      f32x4 v;
#pragma unroll
      for (int j = 0; j < 4; ++j)
        v[j] = x0[(rbase + mt * 16 + g * 4 + j) * 128 + t * 16 + lm];
      xa[mt][t] = v;
      ushort4 hq;
      hq.x = f2h(v[0]); hq.y = f2h(v[1]); hq.z = f2h(v[2]); hq.w = f2h(v[3]);
      xbh[mt][t] = hq;
#pragma unroll
      for (int j = 0; j < 4; ++j)
        stage[mt * 16 + g * 4 + j][t * 16 + lm] = (&hq.x)[j];
    }

  // Prologue: stage W chunk 0 into Wbuf[0] (16 KB; 4 x 16B per thread).
#pragma unroll
  for (int q = 0; q < 4; ++q) {
    int seg = w * 4 + q;
    gload_lds16((const char*)wp + seg * 1024 + lane * 16, Wbuf[0] + seg * 1024);
  }
  __syncthreads();  // Wbuf[0] landed (vmcnt drained), biases visible

#pragma unroll 1
  for (int it = 0; it < 80; ++it) {
    const int s = it & 3;
    const float wgt = (s == 0 || s == 3) ? (0.1f / 6.0f) : (0.1f / 3.0f);
    const float alph = (s < 2) ? 0.05f : 0.1f;

    // x_in A-frags, K=128, held for the whole eval.
    half8 A1[2][4];
#pragma unroll
    for (int mt = 0; mt < 2; ++mt)
#pragma unroll
      for (int ks = 0; ks < 4; ++ks)
        A1[mt][ks] = *(const half8*)&stage[mt * 16 + lm][ks * 32 + g * 8];

    f32x4 yacc[2][8];
#pragma unroll
    for (int mt = 0; mt < 2; ++mt)
#pragma unroll
      for (int t = 0; t < 8; ++t) yacc[mt][t] = f32x4{0.f, 0.f, 0.f, 0.f};

#pragma unroll
    for (int c = 0; c < 16; ++c) {
      // Prefetch next chunk into the other buffer (barrier-protected dbuf).
      {
        const int cn = (c + 1) & 15;
        char* buf = Wbuf[(c + 1) & 1];
        const char* src = (const char*)wp + cn * 16384;
#pragma unroll
        for (int q = 0; q < 4; ++q) {
          int seg = w * 4 + q;
          gload_lds16(src + seg * 1024 + lane * 16, buf + seg * 1024);
        }
      }
      const char* Wb = Wbuf[c & 1];

      // GEMM1: h[32 x 32] = x_in(32x128) @ W1[:, c*32 .. +32)
#pragma unroll
      for (int nt = 0; nt < 2; ++nt) {
        f32x4 h0 = {0.f, 0.f, 0.f, 0.f}, h1 = {0.f, 0.f, 0.f, 0.f};
#pragma unroll
        for (int ks = 0; ks < 4; ++ks) {
          half8 bf = *(const half8*)(Wb + (nt * 4 + ks) * 1024 + lane * 16);
          h0 = __builtin_amdgcn_mfma_f32_16x16x32_f16(A1[0][ks], bf, h0, 0, 0, 0);
          h1 = __builtin_amdgcn_mfma_f32_16x16x32_f16(A1[1][ks], bf, h1, 0, 0, 0);
        }
        float bb = b1s[c * 32 + nt * 16 + lm];
#pragma unroll
        for (int j = 0; j < 4; ++j) {
          stage[g * 4 + j][nt * 16 + lm] = f2h(fmaxf(h0[j] + bb, 0.f));
          stage[16 + g * 4 + j][nt * 16 + lm] = f2h(fmaxf(h1[j] + bb, 0.f));
        }
      }

      // h A-frags (chunk-local K=32) + GEMM2 partial
      half8 A2[2];
#pragma unroll
      for (int mt = 0; mt < 2; ++mt)
        A2[mt] = *(const half8*)&stage[mt * 16 + lm][g * 8];
#pragma unroll
      for (int nt = 0; nt < 8; ++nt) {
        half8 bf = *(const half8*)(Wb + 8192 + nt * 1024 + lane * 16);
        yacc[0][nt] = __builtin_amdgcn_mfma_f32_16x16x32_f16(A2[0], bf, yacc[0][nt], 0, 0, 0);
        yacc[1][nt] = __builtin_amdgcn_mfma_f32_16x16x32_f16(A2[1], bf, yacc[1][nt], 0, 0, 0);
      }
      __syncthreads();  // drains prefetch vmcnt; protects W buffers
    }

    // RK4 combine; write next x_in (fp16) into staging.
#pragma unroll
    for (int mt = 0; mt < 2; ++mt)
#pragma unroll
      for (int t = 0; t < 8; ++t) {
        f32x4 k = yacc[mt][t];
        float bb = b2s[t * 16 + lm];
#pragma unroll
        for (int j = 0; j < 4; ++j) k[j] += bb;
        xa[mt][t] += wgt * k;
        ushort4 hq;
        if (s == 3) {
          f32x4 v = xa[mt][t];
          hq.x = f2h(v[0]); hq.y = f2h(v[1]); hq.z = f2h(v[2]); hq.w = f2h(v[3]);
          xbh[mt][t] = hq;
        } else {
          ushort4 xq = xbh[mt][t];
          hq.x = f2h(h2f(xq.x) + alph * k[0]);
          hq.y = f2h(h2f(xq.y) + alph * k[1]);
          hq.z = f2h(h2f(xq.z) + alph * k[2]);
          hq.w = f2h(h2f(xq.w) + alph * k[3]);
        }
#pragma unroll
        for (int j = 0; j < 4; ++j)
          stage[mt * 16 + g * 4 + j][t * 16 + lm] = (&hq.x)[j];
      }
  }

#pragma unroll
  for (int mt = 0; mt < 2; ++mt)
#pragma unroll
    for (int t = 0; t < 8; ++t)
#pragma unroll
      for (int j = 0; j < 4; ++j)
        out[(rbase + mt * 16 + g * 4 + j) * 128 + t * 16 + lm] = xa[mt][t][j];
}

extern "C" void kernel_launch(void* const* d_in, const int* in_sizes, int n_in,
                              void* d_out, int out_size, void* d_ws, size_t ws_size,
                              hipStream_t stream) {
  const float* x0 = (const float*)d_in[0];
  const float* W1 = (const float*)d_in[1];
  const float* b1 = (const float*)d_in[2];
  const float* W2 = (const float*)d_in[3];
  const float* b2 = (const float*)d_in[4];
  float* out = (float*)d_out;

  unsigned short* wp = (unsigned short*)d_ws;  // 256 frags * 1KB = 256KB

  pack_w<<<64, 256, 0, stream>>>(W1, W2, wp);
  node_rk4<<<512, 256, 0, stream>>>(x0, b1, b2, wp, out);
}

// Round 4
// 2167.647 us; speedup vs baseline: 1.6172x; 1.6172x over previous
//
#include <hip/hip_runtime.h>
#include <stdint.h>

// ===================== Round 4 =====================
// Round-2 data path (proven: absmax 0.03125) + T3/T4 pipeline:
// 4-buffer W ring (4 x 16KB, 32-col chunks), prefetch depth 3,
// raw s_barrier + counted s_waitcnt vmcnt(4) -- never drain to 0
// in the main loop. Ring runs continuously across the 80 evals.
// T5 setprio around MFMA clusters (waves now phase-skewed).
// 256 blocks x 512 threads, 1 block/CU.
// Predict: 1450-1750us, MfmaUtil 36-44%, FETCH <=1GB.
// ===================================================

typedef _Float16 half8 __attribute__((ext_vector_type(8)));
typedef float f32x4 __attribute__((ext_vector_type(4)));
typedef __attribute__((address_space(3))) char lchar;
typedef __attribute__((address_space(1))) char gchar;

#define KSTR 136  // shorts per staging row: 128 + 8 pad -> 272B rows

static __device__ __forceinline__ void gload_lds16(const void* g, void* l) {
  __builtin_amdgcn_global_load_lds((const gchar*)g, (lchar*)l, 16, 0, 0);
}

static __device__ __forceinline__ unsigned short f2h(float x) {
  union { _Float16 h; unsigned short u; } cv;
  cv.h = (_Float16)x;
  return cv.u;
}
static __device__ __forceinline__ float h2f(unsigned short u) {
  union { unsigned short u; _Float16 h; } cv;
  cv.u = u;
  return (float)cv.h;
}

// Prepack W1 (128x512) + W2 (512x128) fp32 -> one fp16 B-frag stream.
// 16 chunks of 32 hidden cols; chunk c occupies 16 KB at wp + c*16384:
//   [0,8K):  W1 frags, f = nt*4 + ks   (nt: 2 of 16 cols, ks: 4 of K=128)
//   [8K,16K): W2 frags, f = 8 + nt     (nt: 8 of 16 out-cols, K-local = 32)
// B-frag (16x16x32): lane l holds B[k][n], n = l&15, k = (l>>4)*8 + j.
__global__ void pack_w(const float* __restrict__ W1, const float* __restrict__ W2,
                       unsigned short* __restrict__ wp) {
  int id = blockIdx.x * 256 + threadIdx.x;  // 0..16383
  int lane = id & 63, fid = (id >> 6) & 255;
  int g = lane >> 4, lm = lane & 15;
  int c = fid >> 4, f = fid & 15;
  if (f < 8) {
    int nt = f >> 2, ks = f & 3;
    int n = c * 32 + nt * 16 + lm;
#pragma unroll
    for (int j = 0; j < 8; ++j) {
      int k = ks * 32 + g * 8 + j;
      wp[fid * 512 + lane * 8 + j] = f2h(W1[k * 512 + n]);
    }
  } else {
    int nt = f - 8;
    int u = nt * 16 + lm;
#pragma unroll
    for (int j = 0; j < 8; ++j) {
      int k = c * 32 + g * 8 + j;
      wp[fid * 512 + lane * 8 + j] = f2h(W2[k * 128 + u]);
    }
  }
}

__global__ __launch_bounds__(512, 2) void node_rk4(
    const float* __restrict__ x0, const float* __restrict__ b1,
    const float* __restrict__ b2, const unsigned short* __restrict__ wp,
    float* __restrict__ out) {
  // LDS: 64K W ring (4 x 16K) + 68K staging + 2.5K biases = 137728 B.
  __shared__ char Wbuf[4][16384];
  __shared__ unsigned short stg[8][32][KSTR];
  __shared__ float b1s[512];
  __shared__ float b2s[128];

  const int tid = threadIdx.x;
  const int w = tid >> 6, lane = tid & 63;
  const int g = lane >> 4, lm = lane & 15;
  unsigned short(*stage)[KSTR] = stg[w];

  b1s[tid] = b1[tid];
  if (tid < 128) b2s[tid] = b2[tid];

  // State: xa fp32 accumulator (C/D layout), xb base as packed fp16.
  const int rbase = blockIdx.x * 256 + w * 32;
  f32x4 xa[2][8];
  ushort4 xbh[2][8];
#pragma unroll
  for (int mt = 0; mt < 2; ++mt)
#pragma unroll
    for (int t = 0; t < 8; ++t) {
      f32x4 v;
#pragma unroll
      for (int j = 0; j < 4; ++j)
        v[j] = x0[(rbase + mt * 16 + g * 4 + j) * 128 + t * 16 + lm];
      xa[mt][t] = v;
      ushort4 hq;
      hq.x = f2h(v[0]); hq.y = f2h(v[1]); hq.z = f2h(v[2]); hq.w = f2h(v[3]);
      xbh[mt][t] = hq;
#pragma unroll
      for (int j = 0; j < 4; ++j)
        stage[mt * 16 + g * 4 + j][t * 16 + lm] = (&hq.x)[j];
    }

  // Prologue: prefetch chunks 0..2 into ring slots 0..2 (2 x 1KB per wave per
  // chunk: wave w owns segs w*2, w*2+1 of 16).
#pragma unroll
  for (int pc = 0; pc < 3; ++pc) {
    const char* src = (const char*)wp + pc * 16384;
#pragma unroll
    for (int q = 0; q < 2; ++q) {
      int seg = w * 2 + q;
      gload_lds16(src + seg * 1024 + lane * 16, Wbuf[pc] + seg * 1024);
    }
  }
  // chunk 0 landed (6 outstanding -> wait to 4), staging/bias writes drained.
  asm volatile("s_waitcnt vmcnt(4) lgkmcnt(0)" ::: "memory");
  __builtin_amdgcn_s_barrier();

#pragma unroll 1
  for (int it = 0; it < 80; ++it) {
    const int s = it & 3;
    const float wgt = (s == 0 || s == 3) ? (0.1f / 6.0f) : (0.1f / 3.0f);
    const float alph = (s < 2) ? 0.05f : 0.1f;

    // x_in A-frags, K=128, held for the whole eval (wave-private staging).
    half8 A1[2][4];
#pragma unroll
    for (int mt = 0; mt < 2; ++mt)
#pragma unroll
      for (int ks = 0; ks < 4; ++ks)
        A1[mt][ks] = *(const half8*)&stage[mt * 16 + lm][ks * 32 + g * 8];

    f32x4 yacc[2][8];
#pragma unroll
    for (int mt = 0; mt < 2; ++mt)
#pragma unroll
      for (int t = 0; t < 8; ++t) yacc[mt][t] = f32x4{0.f, 0.f, 0.f, 0.f};

#pragma unroll
    for (int c = 0; c < 16; ++c) {
      // Issue prefetch for chunk c+3 into ring slot (c+3)&3. Safe: that slot
      // was last read during chunk c-1; the barrier ending c-1 is behind us.
      {
        const int cn = (c + 3) & 15;
        char* buf = Wbuf[(c + 3) & 3];
        const char* src = (const char*)wp + cn * 16384;
#pragma unroll
        for (int q = 0; q < 2; ++q) {
          int seg = w * 2 + q;
          gload_lds16(src + seg * 1024 + lane * 16, buf + seg * 1024);
        }
      }
      const char* Wb = Wbuf[c & 3];

      // GEMM1: h[32 x 32] = x_in(32x128) @ W1[:, c*32 .. +32)
      __builtin_amdgcn_s_setprio(1);
#pragma unroll
      for (int nt = 0; nt < 2; ++nt) {
        f32x4 h0 = {0.f, 0.f, 0.f, 0.f}, h1 = {0.f, 0.f, 0.f, 0.f};
#pragma unroll
        for (int ks = 0; ks < 4; ++ks) {
          half8 bf = *(const half8*)(Wb + (nt * 4 + ks) * 1024 + lane * 16);
          h0 = __builtin_amdgcn_mfma_f32_16x16x32_f16(A1[0][ks], bf, h0, 0, 0, 0);
          h1 = __builtin_amdgcn_mfma_f32_16x16x32_f16(A1[1][ks], bf, h1, 0, 0, 0);
        }
        __builtin_amdgcn_s_setprio(0);
        float bb = b1s[c * 32 + nt * 16 + lm];
#pragma unroll
        for (int j = 0; j < 4; ++j) {
          stage[g * 4 + j][nt * 16 + lm] = f2h(fmaxf(h0[j] + bb, 0.f));
          stage[16 + g * 4 + j][nt * 16 + lm] = f2h(fmaxf(h1[j] + bb, 0.f));
        }
        __builtin_amdgcn_s_setprio(1);
      }

      // h A-frags (chunk-local K=32) + GEMM2 partial
      half8 A2[2];
#pragma unroll
      for (int mt = 0; mt < 2; ++mt)
        A2[mt] = *(const half8*)&stage[mt * 16 + lm][g * 8];
#pragma unroll
      for (int nt = 0; nt < 8; ++nt) {
        half8 bf = *(const half8*)(Wb + 8192 + nt * 1024 + lane * 16);
        yacc[0][nt] = __builtin_amdgcn_mfma_f32_16x16x32_f16(A2[0], bf, yacc[0][nt], 0, 0, 0);
        yacc[1][nt] = __builtin_amdgcn_mfma_f32_16x16x32_f16(A2[1], bf, yacc[1][nt], 0, 0, 0);
      }
      __builtin_amdgcn_s_setprio(0);

      // Counted wait: 6 outstanding (c+1,c+2,c+3) -> wait oldest 2 (c+1's),
      // then rendezvous. Never drains to 0 in the main loop.
      asm volatile("s_waitcnt vmcnt(4)" ::: "memory");
      __builtin_amdgcn_s_barrier();
    }

    // RK4 combine; write next x_in (fp16) into wave-private staging.
#pragma unroll
    for (int mt = 0; mt < 2; ++mt)
#pragma unroll
      for (int t = 0; t < 8; ++t) {
        f32x4 k = yacc[mt][t];
        float bb = b2s[t * 16 + lm];
#pragma unroll
        for (int j = 0; j < 4; ++j) k[j] += bb;
        xa[mt][t] += wgt * k;
        ushort4 hq;
        if (s == 3) {
          f32x4 v = xa[mt][t];
          hq.x = f2h(v[0]); hq.y = f2h(v[1]); hq.z = f2h(v[2]); hq.w = f2h(v[3]);
          xbh[mt][t] = hq;
        } else {
          ushort4 xq = xbh[mt][t];
          hq.x = f2h(h2f(xq.x) + alph * k[0]);
          hq.y = f2h(h2f(xq.y) + alph * k[1]);
          hq.z = f2h(h2f(xq.z) + alph * k[2]);
          hq.w = f2h(h2f(xq.w) + alph * k[3]);
        }
#pragma unroll
        for (int j = 0; j < 4; ++j)
          stage[mt * 16 + g * 4 + j][t * 16 + lm] = (&hq.x)[j];
      }
  }

#pragma unroll
  for (int mt = 0; mt < 2; ++mt)
#pragma unroll
    for (int t = 0; t < 8; ++t)
#pragma unroll
      for (int j = 0; j < 4; ++j)
        out[(rbase + mt * 16 + g * 4 + j) * 128 + t * 16 + lm] = xa[mt][t][j];
}

extern "C" void kernel_launch(void* const* d_in, const int* in_sizes, int n_in,
                              void* d_out, int out_size, void* d_ws, size_t ws_size,
                              hipStream_t stream) {
  const float* x0 = (const float*)d_in[0];
  const float* W1 = (const float*)d_in[1];
  const float* b1 = (const float*)d_in[2];
  const float* W2 = (const float*)d_in[3];
  const float* b2 = (const float*)d_in[4];
  float* out = (float*)d_out;

  unsigned short* wp = (unsigned short*)d_ws;  // 256 frags * 1KB = 256KB

  pack_w<<<64, 256, 0, stream>>>(W1, W2, wp);
  node_rk4<<<256, 512, 0, stream>>>(x0, b1, b2, wp, out);
}

// Round 5
// 2091.478 us; speedup vs baseline: 1.6761x; 1.0364x over previous
//
#include <hip/hip_runtime.h>
#include <stdint.h>

// ===================== Round 5 =====================
// Swapped-operand structure: weights are the MFMA A operand, batch is N.
//   GEMM1': h^T = W1^T (A) x x^T (B);  GEMM2': y^T = W2^T (A) x h^T (B).
// C/D output gives each lane 4 consecutive FEATURES for one batch col ->
// packed ds_write_b64 into [batch][feat] staging; next GEMM's B-frag is a
// single ds_read_b128 (lane=batch l&15, k=(l>>4)*8+j). Kills the 320
// scalar b16 writes/wave/eval (~15k cyc/CU -> ~4k). W ring as R4.
// 256 blocks x 8 waves, batch 32/wave.
// Predict: 1700-1950us, MfmaUtil 30-34, conflicts <=1.5e7, absmax ~0.031.
// ===================================================

typedef _Float16 half8 __attribute__((ext_vector_type(8)));
typedef float f32x4 __attribute__((ext_vector_type(4)));
typedef __attribute__((address_space(3))) char lchar;
typedef __attribute__((address_space(1))) char gchar;

#define XSTR 136  // shorts per xs row (128 + 8 pad), 272B, 16B-aligned
#define HSTR 40   // shorts per hst row (32 + 8 pad), 80B, 16B-aligned

static __device__ __forceinline__ void gload_lds16(const void* g, void* l) {
  __builtin_amdgcn_global_load_lds((const gchar*)g, (lchar*)l, 16, 0, 0);
}

static __device__ __forceinline__ unsigned short f2h(float x) {
  union { _Float16 h; unsigned short u; } cv;
  cv.h = (_Float16)x;
  return cv.u;
}
static __device__ __forceinline__ float h2f(unsigned short u) {
  union { unsigned short u; _Float16 h; } cv;
  cv.u = u;
  return (float)cv.h;
}
static __device__ __forceinline__ uint64_t pack4(float a, float b, float c, float d) {
  union { _Float16 h[4]; uint64_t q; } cv;
  cv.h[0] = (_Float16)a; cv.h[1] = (_Float16)b;
  cv.h[2] = (_Float16)c; cv.h[3] = (_Float16)d;
  return cv.q;
}

// Prepack W1^T / W2^T as MFMA A-frag streams (A[m][k]: m=l&15, k=(l>>4)*8+j).
// 16 chunks of 32 hid; chunk c at wp + c*16384:
//  [0,8K):  W1T frags f = T*4 + ks (T: 2 hid-tiles, ks: 4 of K_in=128)
//           A[m=hid c*32+T*16+lm][k=in ks*32+g*8+j] = W1[k_in*512 + hid]
//  [8K,16K): W2T frags f = 8 + O (O: 8 out-tiles, K_hid = 32 chunk-local)
//           A[m=out O*16+lm][k=hid c*32+g*8+j]      = W2[k_hid*128 + out]
__global__ void pack_w(const float* __restrict__ W1, const float* __restrict__ W2,
                       unsigned short* __restrict__ wp) {
  int id = blockIdx.x * 256 + threadIdx.x;  // 0..16383
  int lane = id & 63, fid = (id >> 6) & 255;
  int g = lane >> 4, lm = lane & 15;
  int c = fid >> 4, f = fid & 15;
  if (f < 8) {
    int T = f >> 2, ks = f & 3;
    int hid = c * 32 + T * 16 + lm;
#pragma unroll
    for (int j = 0; j < 8; ++j) {
      int kin = ks * 32 + g * 8 + j;
      wp[fid * 512 + lane * 8 + j] = f2h(W1[kin * 512 + hid]);
    }
  } else {
    int O = f - 8;
    int of = O * 16 + lm;
#pragma unroll
    for (int j = 0; j < 8; ++j) {
      int kh = c * 32 + g * 8 + j;
      wp[fid * 512 + lane * 8 + j] = f2h(W2[kh * 128 + of]);
    }
  }
}

__global__ __launch_bounds__(512, 2) void node_rk4(
    const float* __restrict__ x0, const float* __restrict__ b1,
    const float* __restrict__ b2, const unsigned short* __restrict__ wp,
    float* __restrict__ out) {
  // LDS: 64K W ring + 68K xs + 20K hst + 2.5K biases = 158,208 B (1 blk/CU).
  __shared__ char Wbuf[4][16384];
  __shared__ __align__(16) unsigned short xs[8][32][XSTR];   // x_in, fp16
  __shared__ __align__(16) unsigned short hst[8][32][HSTR];  // h chunk, fp16
  __shared__ float b1s[512];
  __shared__ float b2s[128];

  const int tid = threadIdx.x;
  const int w = tid >> 6, lane = tid & 63;
  const int g = lane >> 4, lm = lane & 15;

  b1s[tid] = b1[tid];
  if (tid < 128) b2s[tid] = b2[tid];

  // State in swapped C/D layout: lane (g,lm) holds batch col = nt*16+lm,
  // feature rows O*16+4g+j  ->  xa[nt][O][j] fp32, xbh packed fp16.
  const int rbase = blockIdx.x * 256 + w * 32;
  f32x4 xa[2][8];
  ushort4 xbh[2][8];
#pragma unroll
  for (int nt = 0; nt < 2; ++nt)
#pragma unroll
    for (int O = 0; O < 8; ++O) {
      f32x4 v = *(const f32x4*)&x0[(rbase + nt * 16 + lm) * 128 + O * 16 + 4 * g];
      xa[nt][O] = v;
      uint64_t q = pack4(v[0], v[1], v[2], v[3]);
      ushort4 hq;
      *(uint64_t*)&hq = q;
      xbh[nt][O] = hq;
      *(uint64_t*)&xs[w][nt * 16 + lm][O * 16 + 4 * g] = q;
    }

  // Prologue: prefetch W chunks 0..2 into ring slots 0..2.
#pragma unroll
  for (int pc = 0; pc < 3; ++pc) {
    const char* src = (const char*)wp + pc * 16384;
#pragma unroll
    for (int q = 0; q < 2; ++q) {
      int seg = w * 2 + q;
      gload_lds16(src + seg * 1024 + lane * 16, Wbuf[pc] + seg * 1024);
    }
  }
  asm volatile("s_waitcnt vmcnt(4) lgkmcnt(0)" ::: "memory");
  __builtin_amdgcn_s_barrier();

#pragma unroll 1
  for (int it = 0; it < 80; ++it) {
    const int s = it & 3;
    const float wgt = (s == 0 || s == 3) ? (0.1f / 6.0f) : (0.1f / 3.0f);
    const float alph = (s < 2) ? 0.05f : 0.1f;

    // x^T B-frags (K_in=128), held for the whole eval.
    half8 X1[2][4];
#pragma unroll
    for (int nt = 0; nt < 2; ++nt)
#pragma unroll
      for (int ks = 0; ks < 4; ++ks)
        X1[nt][ks] = *(const half8*)&xs[w][nt * 16 + lm][ks * 32 + g * 8];

    f32x4 yacc[2][8];
#pragma unroll
    for (int nt = 0; nt < 2; ++nt)
#pragma unroll
      for (int O = 0; O < 8; ++O) yacc[nt][O] = f32x4{0.f, 0.f, 0.f, 0.f};

#pragma unroll
    for (int c = 0; c < 16; ++c) {
      // Prefetch chunk c+3 into ring slot (c+3)&3 (slot last read chunk c-1).
      {
        const int cn = (c + 3) & 15;
        char* buf = Wbuf[(c + 3) & 3];
        const char* src = (const char*)wp + cn * 16384;
#pragma unroll
        for (int q = 0; q < 2; ++q) {
          int seg = w * 2 + q;
          gload_lds16(src + seg * 1024 + lane * 16, buf + seg * 1024);
        }
      }
      const char* Wb = Wbuf[c & 3];

      // GEMM1': h^T tiles (hid 32 x batch 32).
      __builtin_amdgcn_s_setprio(1);
#pragma unroll
      for (int T = 0; T < 2; ++T) {
        f32x4 h0 = {0.f, 0.f, 0.f, 0.f}, h1 = {0.f, 0.f, 0.f, 0.f};
#pragma unroll
        for (int ks = 0; ks < 4; ++ks) {
          half8 wa = *(const half8*)(Wb + (T * 4 + ks) * 1024 + lane * 16);
          h0 = __builtin_amdgcn_mfma_f32_16x16x32_f16(wa, X1[0][ks], h0, 0, 0, 0);
          h1 = __builtin_amdgcn_mfma_f32_16x16x32_f16(wa, X1[1][ks], h1, 0, 0, 0);
        }
        __builtin_amdgcn_s_setprio(0);
        f32x4 bb = *(const f32x4*)&b1s[c * 32 + T * 16 + 4 * g];
        uint64_t p0 = pack4(fmaxf(h0[0] + bb[0], 0.f), fmaxf(h0[1] + bb[1], 0.f),
                            fmaxf(h0[2] + bb[2], 0.f), fmaxf(h0[3] + bb[3], 0.f));
        uint64_t p1 = pack4(fmaxf(h1[0] + bb[0], 0.f), fmaxf(h1[1] + bb[1], 0.f),
                            fmaxf(h1[2] + bb[2], 0.f), fmaxf(h1[3] + bb[3], 0.f));
        *(uint64_t*)&hst[w][lm][T * 16 + 4 * g] = p0;
        *(uint64_t*)&hst[w][16 + lm][T * 16 + 4 * g] = p1;
        __builtin_amdgcn_s_setprio(1);
      }

      // h^T B-frags (K_hid = 32, chunk-local) + GEMM2' partial.
      half8 H20 = *(const half8*)&hst[w][lm][g * 8];
      half8 H21 = *(const half8*)&hst[w][16 + lm][g * 8];
#pragma unroll
      for (int O = 0; O < 8; ++O) {
        half8 wa = *(const half8*)(Wb + 8192 + O * 1024 + lane * 16);
        yacc[0][O] = __builtin_amdgcn_mfma_f32_16x16x32_f16(wa, H20, yacc[0][O], 0, 0, 0);
        yacc[1][O] = __builtin_amdgcn_mfma_f32_16x16x32_f16(wa, H21, yacc[1][O], 0, 0, 0);
      }
      __builtin_amdgcn_s_setprio(0);

      // Counted wait (6 outstanding -> oldest 2 done) + rendezvous.
      asm volatile("s_waitcnt vmcnt(4)" ::: "memory");
      __builtin_amdgcn_s_barrier();
    }

    // RK4 combine; write next x_in (packed b64) into xs.
#pragma unroll
    for (int nt = 0; nt < 2; ++nt)
#pragma unroll
      for (int O = 0; O < 8; ++O) {
        f32x4 bb2 = *(const f32x4*)&b2s[O * 16 + 4 * g];
        f32x4 k = yacc[nt][O];
#pragma unroll
        for (int j = 0; j < 4; ++j) k[j] += bb2[j];
        xa[nt][O] += wgt * k;
        uint64_t q;
        if (s == 3) {
          f32x4 v = xa[nt][O];
          q = pack4(v[0], v[1], v[2], v[3]);
          ushort4 hq;
          *(uint64_t*)&hq = q;
          xbh[nt][O] = hq;
        } else {
          ushort4 xq = xbh[nt][O];
          q = pack4(h2f(xq.x) + alph * k[0], h2f(xq.y) + alph * k[1],
                    h2f(xq.z) + alph * k[2], h2f(xq.w) + alph * k[3]);
        }
        *(uint64_t*)&xs[w][nt * 16 + lm][O * 16 + 4 * g] = q;
      }
  }

#pragma unroll
  for (int nt = 0; nt < 2; ++nt)
#pragma unroll
    for (int O = 0; O < 8; ++O)
      *(f32x4*)&out[(rbase + nt * 16 + lm) * 128 + O * 16 + 4 * g] = xa[nt][O];
}

extern "C" void kernel_launch(void* const* d_in, const int* in_sizes, int n_in,
                              void* d_out, int out_size, void* d_ws, size_t ws_size,
                              hipStream_t stream) {
  const float* x0 = (const float*)d_in[0];
  const float* W1 = (const float*)d_in[1];
  const float* b1 = (const float*)d_in[2];
  const float* W2 = (const float*)d_in[3];
  const float* b2 = (const float*)d_in[4];
  float* out = (float*)d_out;

  unsigned short* wp = (unsigned short*)d_ws;  // 256 frags * 1KB = 256KB

  pack_w<<<64, 256, 0, stream>>>(W1, W2, wp);
  node_rk4<<<256, 512, 0, stream>>>(x0, b1, b2, wp, out);
}

// Round 6
// 1930.068 us; speedup vs baseline: 1.8163x; 1.0836x over previous
//
#include <hip/hip_runtime.h>
#include <stdint.h>

// ===================== Round 6 =====================
// R5 swapped-operand structure + software-pipelined chunks:
// GEMM2 runs one chunk BEHIND GEMM1 (reads h(c-1) written a full
// chunk earlier -> no mid-chunk lgkmcnt turnaround; 32 independent
// MFMAs per body for LDS/MFMA/VALU overlap). W ring 4 x 16KB,
// prefetch depth 2, s_waitcnt vmcnt(2) + raw barrier per chunk.
// Identical arithmetic order to R5 -> absmax 0.03125 expected.
// Predict: 1500-1800us, MfmaUtil 33-40, VALU 27-33.
// ===================================================

typedef _Float16 half8 __attribute__((ext_vector_type(8)));
typedef float f32x4 __attribute__((ext_vector_type(4)));
typedef __attribute__((address_space(3))) char lchar;
typedef __attribute__((address_space(1))) char gchar;

#define XSTR 136  // shorts per xs row (128 + 8 pad), 272B
#define HSTR 40   // shorts per hst row (32 + 8 pad), 80B

static __device__ __forceinline__ void gload_lds16(const void* g, void* l) {
  __builtin_amdgcn_global_load_lds((const gchar*)g, (lchar*)l, 16, 0, 0);
}

static __device__ __forceinline__ unsigned short f2h(float x) {
  union { _Float16 h; unsigned short u; } cv;
  cv.h = (_Float16)x;
  return cv.u;
}
static __device__ __forceinline__ float h2f(unsigned short u) {
  union { unsigned short u; _Float16 h; } cv;
  cv.u = u;
  return (float)cv.h;
}
static __device__ __forceinline__ uint64_t pack4(float a, float b, float c, float d) {
  union { _Float16 h[4]; uint64_t q; } cv;
  cv.h[0] = (_Float16)a; cv.h[1] = (_Float16)b;
  cv.h[2] = (_Float16)c; cv.h[3] = (_Float16)d;
  return cv.q;
}

// Prepack W1^T / W2^T as MFMA A-frag streams (A[m][k]: m=l&15, k=(l>>4)*8+j).
// 16 chunks of 32 hid; chunk c at wp + c*16384:
//  [0,8K):  W1T frags f = T*4 + ks (T: 2 hid-tiles, ks: 4 of K_in=128)
//  [8K,16K): W2T frags f = 8 + O (O: 8 out-tiles, K_hid = 32 chunk-local)
__global__ void pack_w(const float* __restrict__ W1, const float* __restrict__ W2,
                       unsigned short* __restrict__ wp) {
  int id = blockIdx.x * 256 + threadIdx.x;  // 0..16383
  int lane = id & 63, fid = (id >> 6) & 255;
  int g = lane >> 4, lm = lane & 15;
  int c = fid >> 4, f = fid & 15;
  if (f < 8) {
    int T = f >> 2, ks = f & 3;
    int hid = c * 32 + T * 16 + lm;
#pragma unroll
    for (int j = 0; j < 8; ++j) {
      int kin = ks * 32 + g * 8 + j;
      wp[fid * 512 + lane * 8 + j] = f2h(W1[kin * 512 + hid]);
    }
  } else {
    int O = f - 8;
    int of = O * 16 + lm;
#pragma unroll
    for (int j = 0; j < 8; ++j) {
      int kh = c * 32 + g * 8 + j;
      wp[fid * 512 + lane * 8 + j] = f2h(W2[kh * 128 + of]);
    }
  }
}

__global__ __launch_bounds__(512, 2) void node_rk4(
    const float* __restrict__ x0, const float* __restrict__ b1,
    const float* __restrict__ b2, const unsigned short* __restrict__ wp,
    float* __restrict__ out) {
  __shared__ char Wbuf[4][16384];
  __shared__ __align__(16) unsigned short xs[8][32][XSTR];   // x_in, fp16
  __shared__ __align__(16) unsigned short hst[8][32][HSTR];  // h chunk, fp16
  __shared__ float b1s[512];
  __shared__ float b2s[128];

  const int tid = threadIdx.x;
  const int w = tid >> 6, lane = tid & 63;
  const int g = lane >> 4, lm = lane & 15;

  b1s[tid] = b1[tid];
  if (tid < 128) b2s[tid] = b2[tid];

  // State: lane (g,lm) holds batch col nt*16+lm, feature rows O*16+4g+j.
  const int rbase = blockIdx.x * 256 + w * 32;
  f32x4 xa[2][8];
  ushort4 xbh[2][8];
#pragma unroll
  for (int nt = 0; nt < 2; ++nt)
#pragma unroll
    for (int O = 0; O < 8; ++O) {
      f32x4 v = *(const f32x4*)&x0[(rbase + nt * 16 + lm) * 128 + O * 16 + 4 * g];
      xa[nt][O] = v;
      uint64_t q = pack4(v[0], v[1], v[2], v[3]);
      ushort4 hq;
      *(uint64_t*)&hq = q;
      xbh[nt][O] = hq;
      *(uint64_t*)&xs[w][nt * 16 + lm][O * 16 + 4 * g] = q;
    }

  // Prologue: prefetch W chunks 0,1 into ring slots 0,1 (depth 2).
#pragma unroll
  for (int pc = 0; pc < 2; ++pc) {
    const char* src = (const char*)wp + pc * 16384;
#pragma unroll
    for (int q = 0; q < 2; ++q) {
      int seg = w * 2 + q;
      gload_lds16(src + seg * 1024 + lane * 16, Wbuf[pc] + seg * 1024);
    }
  }
  asm volatile("s_waitcnt vmcnt(2) lgkmcnt(0)" ::: "memory");
  __builtin_amdgcn_s_barrier();

#pragma unroll 1
  for (int it = 0; it < 80; ++it) {
    const int s = it & 3;
    const float wgt = (s == 0 || s == 3) ? (0.1f / 6.0f) : (0.1f / 3.0f);
    const float alph = (s < 2) ? 0.05f : 0.1f;

    // x^T B-frags (K_in=128), held for the whole eval.
    half8 X1[2][4];
#pragma unroll
    for (int nt = 0; nt < 2; ++nt)
#pragma unroll
      for (int ks = 0; ks < 4; ++ks)
        X1[nt][ks] = *(const half8*)&xs[w][nt * 16 + lm][ks * 32 + g * 8];

    f32x4 yacc[2][8];
#pragma unroll
    for (int nt = 0; nt < 2; ++nt)
#pragma unroll
      for (int O = 0; O < 8; ++O) yacc[nt][O] = f32x4{0.f, 0.f, 0.f, 0.f};

#pragma unroll
    for (int c = 0; c < 16; ++c) {
      // h(c-1) B-frags: written one full chunk ago (no lgkm turnaround).
      // Program order before this iter's hst writes; same-array aliasing
      // forbids reordering.
      half8 Hp0, Hp1;
      if (c > 0) {
        Hp0 = *(const half8*)&hst[w][lm][g * 8];
        Hp1 = *(const half8*)&hst[w][16 + lm][g * 8];
      }

      // Prefetch chunk (c+2)&15 into ring slot (c+2)&3.
      // Live slots this iter: (c-1) GEMM2-read, (c) GEMM1-read, (c+1) landed.
      {
        const int cn = (c + 2) & 15;
        char* buf = Wbuf[(c + 2) & 3];
        const char* src = (const char*)wp + cn * 16384;
#pragma unroll
        for (int q = 0; q < 2; ++q) {
          int seg = w * 2 + q;
          gload_lds16(src + seg * 1024 + lane * 16, buf + seg * 1024);
        }
      }

      __builtin_amdgcn_s_setprio(1);
      // GEMM2'(c-1): y^T += W2T(c-1) x h^T(c-1).
      if (c > 0) {
        const char* Wp = Wbuf[(c + 3) & 3];  // == (c-1)&3
#pragma unroll
        for (int O = 0; O < 8; ++O) {
          half8 wa = *(const half8*)(Wp + 8192 + O * 1024 + lane * 16);
          yacc[0][O] = __builtin_amdgcn_mfma_f32_16x16x32_f16(wa, Hp0, yacc[0][O], 0, 0, 0);
          yacc[1][O] = __builtin_amdgcn_mfma_f32_16x16x32_f16(wa, Hp1, yacc[1][O], 0, 0, 0);
        }
      }

      // GEMM1'(c): h^T tiles (hid 32 x batch 32).
      const char* Wb = Wbuf[c & 3];
#pragma unroll
      for (int T = 0; T < 2; ++T) {
        f32x4 h0 = {0.f, 0.f, 0.f, 0.f}, h1 = {0.f, 0.f, 0.f, 0.f};
#pragma unroll
        for (int ks = 0; ks < 4; ++ks) {
          half8 wa = *(const half8*)(Wb + (T * 4 + ks) * 1024 + lane * 16);
          h0 = __builtin_amdgcn_mfma_f32_16x16x32_f16(wa, X1[0][ks], h0, 0, 0, 0);
          h1 = __builtin_amdgcn_mfma_f32_16x16x32_f16(wa, X1[1][ks], h1, 0, 0, 0);
        }
        __builtin_amdgcn_s_setprio(0);
        f32x4 bb = *(const f32x4*)&b1s[c * 32 + T * 16 + 4 * g];
        uint64_t p0 = pack4(fmaxf(h0[0] + bb[0], 0.f), fmaxf(h0[1] + bb[1], 0.f),
                            fmaxf(h0[2] + bb[2], 0.f), fmaxf(h0[3] + bb[3], 0.f));
        uint64_t p1 = pack4(fmaxf(h1[0] + bb[0], 0.f), fmaxf(h1[1] + bb[1], 0.f),
                            fmaxf(h1[2] + bb[2], 0.f), fmaxf(h1[3] + bb[3], 0.f));
        *(uint64_t*)&hst[w][lm][T * 16 + 4 * g] = p0;
        *(uint64_t*)&hst[w][16 + lm][T * 16 + 4 * g] = p1;
        __builtin_amdgcn_s_setprio(1);
      }
      __builtin_amdgcn_s_setprio(0);

      // Counted wait: outstanding {c+1, c+2} x2 loads; ensure c+1 landed.
      asm volatile("s_waitcnt vmcnt(2)" ::: "memory");
      __builtin_amdgcn_s_barrier();
    }

    // Tail GEMM2'(15): one lgkm turnaround per eval.
    {
      half8 Hl0 = *(const half8*)&hst[w][lm][g * 8];
      half8 Hl1 = *(const half8*)&hst[w][16 + lm][g * 8];
      const char* Wp = Wbuf[3];  // 15 & 3
#pragma unroll
      for (int O = 0; O < 8; ++O) {
        half8 wa = *(const half8*)(Wp + 8192 + O * 1024 + lane * 16);
        yacc[0][O] = __builtin_amdgcn_mfma_f32_16x16x32_f16(wa, Hl0, yacc[0][O], 0, 0, 0);
        yacc[1][O] = __builtin_amdgcn_mfma_f32_16x16x32_f16(wa, Hl1, yacc[1][O], 0, 0, 0);
      }
    }

    // RK4 combine; write next x_in (packed b64) into xs.
#pragma unroll
    for (int nt = 0; nt < 2; ++nt)
#pragma unroll
      for (int O = 0; O < 8; ++O) {
        f32x4 bb2 = *(const f32x4*)&b2s[O * 16 + 4 * g];
        f32x4 k = yacc[nt][O];
#pragma unroll
        for (int j = 0; j < 4; ++j) k[j] += bb2[j];
        xa[nt][O] += wgt * k;
        uint64_t q;
        if (s == 3) {
          f32x4 v = xa[nt][O];
          q = pack4(v[0], v[1], v[2], v[3]);
          ushort4 hq;
          *(uint64_t*)&hq = q;
          xbh[nt][O] = hq;
        } else {
          ushort4 xq = xbh[nt][O];
          q = pack4(h2f(xq.x) + alph * k[0], h2f(xq.y) + alph * k[1],
                    h2f(xq.z) + alph * k[2], h2f(xq.w) + alph * k[3]);
        }
        *(uint64_t*)&xs[w][nt * 16 + lm][O * 16 + 4 * g] = q;
      }
  }

#pragma unroll
  for (int nt = 0; nt < 2; ++nt)
#pragma unroll
    for (int O = 0; O < 8; ++O)
      *(f32x4*)&out[(rbase + nt * 16 + lm) * 128 + O * 16 + 4 * g] = xa[nt][O];
}

extern "C" void kernel_launch(void* const* d_in, const int* in_sizes, int n_in,
                              void* d_out, int out_size, void* d_ws, size_t ws_size,
                              hipStream_t stream) {
  const float* x0 = (const float*)d_in[0];
  const float* W1 = (const float*)d_in[1];
  const float* b1 = (const float*)d_in[2];
  const float* W2 = (const float*)d_in[3];
  const float* b2 = (const float*)d_in[4];
  float* out = (float*)d_out;

  unsigned short* wp = (unsigned short*)d_ws;  // 256 frags * 1KB = 256KB

  pack_w<<<64, 256, 0, stream>>>(W1, W2, wp);
  node_rk4<<<256, 512, 0, stream>>>(x0, b1, b2, wp, out);
}